// Round 12
// baseline (709.604 us; speedup 1.0000x reference)
//
#include <hip/hip_runtime.h>
#include <hip/hip_bf16.h>
#include <hip/hip_cooperative_groups.h>

namespace cg = cooperative_groups;

// Problem constants
#define NB   64
#define NCDD 5
#define NHIS 100
#define ND   256
#define NK   10
#define TLD  23040          // T*L*D = 30*3*256
#define THRESH 0.1f
#define NEG_INF (-3.402823466e38f)
#define NROWS_HIS 6400      // 64*100
#define NROWS_CDD 320       // 64*5
#define GRID 1024           // 4 blocks/CU x 256 CUs

typedef float f32x4 __attribute__((ext_vector_type(4)));

// ===========================================================================
// FALLBACK PATH: the proven R8/R9 3-kernel pipeline (byte-identical bodies).
// ===========================================================================
__global__ __launch_bounds__(256) void proj_norm_all(
    const float* __restrict__ his_repr,
    const float* __restrict__ cdd_repr,
    const float* __restrict__ W,
    const float* __restrict__ bvec,
    float* __restrict__ Yall)
{
    __shared__ float red[4][8];
    const int r0  = blockIdx.x * 8;
    const int tid = threadIdx.x;
    const int sub = tid & 3;
    const int grp = tid >> 2;
    const int wave = tid >> 6, lane = tid & 63;

    const float* __restrict__ X = (r0 < NROWS_HIS)
        ? (his_repr + (size_t)r0 * ND)
        : (cdd_repr + (size_t)(r0 - NROWS_HIS) * ND);

    float acc[4][8];
#pragma unroll
    for (int p = 0; p < 4; ++p)
#pragma unroll
        for (int r = 0; r < 8; ++r) acc[p][r] = 0.f;

#pragma unroll 4
    for (int i = 0; i < 16; ++i) {
        const int kb = sub * 4 + 16 * i;
        float4 x4[8];
#pragma unroll
        for (int r = 0; r < 8; ++r)
            x4[r] = *(const float4*)(X + (size_t)r * ND + kb);
#pragma unroll
        for (int p = 0; p < 4; ++p) {
            const int d = p * 64 + grp;
            const float4 w4 = *(const float4*)(W + (size_t)d * ND + kb);
#pragma unroll
            for (int r = 0; r < 8; ++r)
                acc[p][r] += w4.x * x4[r].x + w4.y * x4[r].y
                           + w4.z * x4[r].z + w4.w * x4[r].w;
        }
    }

#pragma unroll
    for (int p = 0; p < 4; ++p)
#pragma unroll
        for (int r = 0; r < 8; ++r) {
            float v = acc[p][r];
            v += __shfl_xor(v, 1);
            v += __shfl_xor(v, 2);
            acc[p][r] = v;
        }

    float bias[4];
#pragma unroll
    for (int p = 0; p < 4; ++p) bias[p] = bvec[p * 64 + grp];

    float ss[8];
#pragma unroll
    for (int r = 0; r < 8; ++r) {
        float t = 0.f;
#pragma unroll
        for (int p = 0; p < 4; ++p) {
            const float y = acc[p][r] + bias[p];
            acc[p][r] = y;
            t += y * y;
        }
        for (int off = 32; off; off >>= 1) t += __shfl_xor(t, off);
        ss[r] = t;
    }
    if (lane == 0) {
#pragma unroll
        for (int r = 0; r < 8; ++r) red[wave][r] = ss[r];
    }
    __syncthreads();

#pragma unroll
    for (int r = 0; r < 8; ++r) {
        const float s = 0.25f * (red[0][r] + red[1][r] + red[2][r] + red[3][r]);
        const float scale = 1.0f / fmaxf(sqrtf(s), 1e-12f);
        if (sub == 0) {
#pragma unroll
            for (int p = 0; p < 4; ++p)
                Yall[(size_t)(r0 + r) * ND + p * 64 + grp] = acc[p][r] * scale;
        }
    }
}

__global__ __launch_bounds__(512) void attn_topk_kernel(
    const float* __restrict__ cdd_p,
    const float* __restrict__ his_p,
    float* __restrict__ out_idx_f,
    int* __restrict__ ws_idx,
    float* __restrict__ ws_w)
{
    __shared__ float attn_s[NCDD][128];
    const int b   = blockIdx.x;
    const int tid = threadIdx.x;
    const int sub = tid & 3, grp = tid >> 2;
    const int wave = tid >> 6, lane = tid & 63;

    const float* __restrict__ cbase = cdd_p + (size_t)b * NCDD * ND;
    const float* __restrict__ hbase = his_p + (size_t)b * NHIS * ND;

#pragma unroll
    for (int it = 0; it < 4; ++it) {
        const int task = it * 128 + grp;
        if (task < NCDD * NHIS) {
            const int c = task / NHIS, h = task - c * NHIS;
            const float* __restrict__ crow = cbase + (size_t)c * ND;
            const float* __restrict__ hrow = hbase + (size_t)h * ND;
            float a = 0.f;
#pragma unroll
            for (int i = 0; i < 16; ++i) {
                const int kb = sub * 4 + 16 * i;
                const float4 cv = *(const float4*)(crow + kb);
                const float4 hv = *(const float4*)(hrow + kb);
                a += cv.x * hv.x + cv.y * hv.y + cv.z * hv.z + cv.w * hv.w;
            }
            a += __shfl_xor(a, 1);
            a += __shfl_xor(a, 2);
            if (sub == 0) attn_s[c][h] = a;
        }
    }
    __syncthreads();

    if (wave < NCDD) {
        const int c = wave;
        float v0 = attn_s[c][lane];
        float v1 = (lane + 64 < NHIS) ? attn_s[c][lane + 64] : NEG_INF;
#pragma unroll
        for (int k = 0; k < NK; ++k) {
            float lv; int li;
            if (v1 > v0) { lv = v1; li = lane + 64; }
            else         { lv = v0; li = lane; }
            for (int off = 1; off < 64; off <<= 1) {
                const float ov = __shfl_xor(lv, off);
                const int   oi = __shfl_xor(li, off);
                if (ov > lv || (ov == lv && oi < li)) { lv = ov; li = oi; }
            }
            if (lane == 0) {
                const float w = (lv < THRESH) ? 0.0f : lv;
                const int g = (b * NCDD + c) * NK + k;
                ws_idx[g] = li;
                ws_w[g]   = w;
                out_idx_f[g] = (float)li;
            }
            if (li == lane)            v0 = NEG_INF;
            else if (li == lane + 64)  v1 = NEG_INF;
        }
    }
}

__global__ __launch_bounds__(256) void gather_kernel(
    const float* __restrict__ his_emb,
    const int* __restrict__ ws_idx,
    const float* __restrict__ ws_w,
    float* __restrict__ out)
{
    const int orig = blockIdx.x;
    const int g = (orig & 7) * 400 + (orig >> 3);
    const int b = g / (NCDD * NK);
    const int tid = threadIdx.x;
    const float w = ws_w[g];

    f32x4* __restrict__ dst = (f32x4*)(out + (size_t)g * TLD);

    if (w == 0.0f) {
        const f32x4 z = {0.f, 0.f, 0.f, 0.f};
#pragma unroll
        for (int it = 0; it < 22; ++it) dst[tid + it * 256] = z;
        if (tid < 128) dst[22 * 256 + tid] = z;
        return;
    }

    const int idx = ws_idx[g];
    const f32x4* __restrict__ src =
        (const f32x4*)(his_emb + ((size_t)b * NHIS + idx) * TLD);

    f32x4 v[22];
    f32x4 vt;
#pragma unroll
    for (int j = 0; j < 22; ++j) v[j] = src[tid + j * 256];
    const bool tail = (tid < 128);
    if (tail) vt = src[22 * 256 + tid];

#pragma unroll
    for (int j = 0; j < 22; ++j) dst[tid + j * 256] = v[j] * w;
    if (tail) dst[22 * 256 + tid] = vt * w;
}

// ===========================================================================
// COOPERATIVE PATH: same three phases in one kernel, with explicit
// agent-scope fences (__threadfence -> L2 writeback/inv on gfx950) around
// each grid.sync to force cross-XCD visibility of Yall / ws_idx / ws_w.
// ===========================================================================
__global__ __launch_bounds__(256, 4) void fused_all(
    const float* __restrict__ his_repr,
    const float* __restrict__ cdd_repr,
    const float* __restrict__ W,
    const float* __restrict__ bvec,
    const float* __restrict__ his_emb,
    float* __restrict__ Yall,
    int*   __restrict__ ws_idx,
    float* __restrict__ ws_w,
    float* __restrict__ out_idx_f,
    float* __restrict__ out)
{
    cg::grid_group grid = cg::this_grid();

    __shared__ float red[4][8];
    __shared__ float attn_s[128];

    const int tid = threadIdx.x;
    const int sub = tid & 3, grp = tid >> 2;
    const int wave = tid >> 6, lane = tid & 63;

    // ======== Phase 1: projection + L2-norm (840 units of 8 rows) ========
    for (int u = blockIdx.x; u < (NROWS_HIS + NROWS_CDD) / 8; u += GRID) {
        const int r0 = u * 8;
        const float* __restrict__ X = (r0 < NROWS_HIS)
            ? (his_repr + (size_t)r0 * ND)
            : (cdd_repr + (size_t)(r0 - NROWS_HIS) * ND);

        float acc[4][8];
#pragma unroll
        for (int p = 0; p < 4; ++p)
#pragma unroll
            for (int r = 0; r < 8; ++r) acc[p][r] = 0.f;

#pragma unroll 4
        for (int i = 0; i < 16; ++i) {
            const int kb = sub * 4 + 16 * i;
            float4 x4[8];
#pragma unroll
            for (int r = 0; r < 8; ++r)
                x4[r] = *(const float4*)(X + (size_t)r * ND + kb);
#pragma unroll
            for (int p = 0; p < 4; ++p) {
                const int d = p * 64 + grp;
                const float4 w4 = *(const float4*)(W + (size_t)d * ND + kb);
#pragma unroll
                for (int r = 0; r < 8; ++r)
                    acc[p][r] += w4.x * x4[r].x + w4.y * x4[r].y
                               + w4.z * x4[r].z + w4.w * x4[r].w;
            }
        }

#pragma unroll
        for (int p = 0; p < 4; ++p)
#pragma unroll
            for (int r = 0; r < 8; ++r) {
                float v = acc[p][r];
                v += __shfl_xor(v, 1);
                v += __shfl_xor(v, 2);
                acc[p][r] = v;
            }

        float bias[4];
#pragma unroll
        for (int p = 0; p < 4; ++p) bias[p] = bvec[p * 64 + grp];

        float ss[8];
#pragma unroll
        for (int r = 0; r < 8; ++r) {
            float t = 0.f;
#pragma unroll
            for (int p = 0; p < 4; ++p) {
                const float y = acc[p][r] + bias[p];
                acc[p][r] = y;
                t += y * y;
            }
            for (int off = 32; off; off >>= 1) t += __shfl_xor(t, off);
            ss[r] = t;
        }
        if (lane == 0) {
#pragma unroll
            for (int r = 0; r < 8; ++r) red[wave][r] = ss[r];
        }
        __syncthreads();

#pragma unroll
        for (int r = 0; r < 8; ++r) {
            const float s = 0.25f * (red[0][r] + red[1][r] + red[2][r] + red[3][r]);
            const float scale = 1.0f / fmaxf(sqrtf(s), 1e-12f);
            if (sub == 0) {
#pragma unroll
                for (int p = 0; p < 4; ++p)
                    Yall[(size_t)(r0 + r) * ND + p * 64 + grp] = acc[p][r] * scale;
            }
        }
        __syncthreads();
    }

    __threadfence();     // release: push Yall out of this XCD's L2
    grid.sync();
    __threadfence();     // acquire: invalidate stale lines before reading Yall

    // ======== Phase 2: attn + exact top-10, one block per (b,c) ========
    if (blockIdx.x < NB * NCDD) {
        const int bc = blockIdx.x;
        const int b  = bc / NCDD;
        const float* __restrict__ crow = Yall + ((size_t)NROWS_HIS + bc) * ND;
        const float* __restrict__ hbase = Yall + (size_t)b * NHIS * ND;

        {
            const int h0 = grp, h1 = grp + 64;
            const float* __restrict__ h0row = hbase + (size_t)h0 * ND;
            const float* __restrict__ h1row = hbase + (size_t)h1 * ND;
            float a0 = 0.f, a1 = 0.f;
#pragma unroll
            for (int i = 0; i < 16; ++i) {
                const int kb = sub * 4 + 16 * i;
                const float4 cv = *(const float4*)(crow + kb);
                const float4 v0 = *(const float4*)(h0row + kb);
                a0 += cv.x * v0.x + cv.y * v0.y + cv.z * v0.z + cv.w * v0.w;
                if (h1 < NHIS) {
                    const float4 v1 = *(const float4*)(h1row + kb);
                    a1 += cv.x * v1.x + cv.y * v1.y + cv.z * v1.z + cv.w * v1.w;
                }
            }
            a0 += __shfl_xor(a0, 1); a0 += __shfl_xor(a0, 2);
            a1 += __shfl_xor(a1, 1); a1 += __shfl_xor(a1, 2);
            if (sub == 0) {
                attn_s[h0] = a0;
                if (h1 < NHIS) attn_s[h1] = a1;
            }
        }
        __syncthreads();

        if (wave == 0) {
            float v0 = attn_s[lane];
            float v1 = (lane + 64 < NHIS) ? attn_s[lane + 64] : NEG_INF;
#pragma unroll
            for (int kk = 0; kk < NK; ++kk) {
                float lv; int li;
                if (v1 > v0) { lv = v1; li = lane + 64; }
                else         { lv = v0; li = lane; }
                for (int off = 1; off < 64; off <<= 1) {
                    const float ov = __shfl_xor(lv, off);
                    const int   oi = __shfl_xor(li, off);
                    if (ov > lv || (ov == lv && oi < li)) { lv = ov; li = oi; }
                }
                if (lane == 0) {
                    const float w = (lv < THRESH) ? 0.0f : lv;
                    const int g = bc * NK + kk;
                    ws_idx[g] = li;
                    ws_w[g]   = w;
                    out_idx_f[g] = (float)li;
                }
                if (li == lane)            v0 = NEG_INF;
                else if (li == lane + 64)  v1 = NEG_INF;
            }
        }
    }

    __threadfence();     // release ws_idx/ws_w
    grid.sync();
    __threadfence();     // acquire before reading ws_idx/ws_w

    // ======== Phase 3: gather + scale (R9 body, grid-strided) ========
    for (int u = blockIdx.x; u < NB * NCDD * NK; u += GRID) {
        const int g = (u & 7) * 400 + (u >> 3);
        const int b = g / (NCDD * NK);
        const float w = ws_w[g];

        f32x4* __restrict__ dst = (f32x4*)(out + (size_t)g * TLD);

        if (w == 0.0f) {
            const f32x4 z = {0.f, 0.f, 0.f, 0.f};
#pragma unroll
            for (int it = 0; it < 22; ++it) dst[tid + it * 256] = z;
            if (tid < 128) dst[22 * 256 + tid] = z;
            continue;
        }

        const int idx = ws_idx[g];
        const f32x4* __restrict__ src =
            (const f32x4*)(his_emb + ((size_t)b * NHIS + idx) * TLD);

        f32x4 v[22];
        f32x4 vt;
#pragma unroll
        for (int j = 0; j < 22; ++j) v[j] = src[tid + j * 256];
        const bool tail = (tid < 128);
        if (tail) vt = src[22 * 256 + tid];

#pragma unroll
        for (int j = 0; j < 22; ++j) dst[tid + j * 256] = v[j] * w;
        if (tail) dst[22 * 256 + tid] = vt * w;
    }
}

// ---------------------------------------------------------------------------
extern "C" void kernel_launch(void* const* d_in, const int* in_sizes, int n_in,
                              void* d_out, int out_size, void* d_ws, size_t ws_size,
                              hipStream_t stream)
{
    const float* cdd_repr = (const float*)d_in[0];   // (64,5,256)
    const float* his_repr = (const float*)d_in[1];   // (64,100,256)
    const float* his_emb  = (const float*)d_in[2];   // (64,100,30,3,256)
    const float* W_sel    = (const float*)d_in[3];   // (256,256)
    const float* b_sel    = (const float*)d_in[4];   // (256,)
    float* out = (float*)d_out;

    // Workspace layout
    char* ws = (char*)d_ws;
    float* Yall  = (float*)ws;                       // 6720 rows * 256 * 4
    float* his_p = Yall;                             // rows [0, 6400)
    float* cdd_p = Yall + (size_t)NROWS_HIS * ND;    // rows [6400, 6720)
    int*   idx_i = (int*)  (ws + 6881280);           // 3200*4
    float* w_w   = (float*)(ws + 6894080);           // 3200*4

    // Output: his_activated [73,728,000] then idx [3200] (as float values)
    float* out_idx_f = out + (size_t)NB * NCDD * NK * TLD;

    void* args[] = {
        (void*)&his_repr, (void*)&cdd_repr, (void*)&W_sel, (void*)&b_sel,
        (void*)&his_emb,  (void*)&Yall,     (void*)&idx_i, (void*)&w_w,
        (void*)&out_idx_f, (void*)&out
    };
    hipError_t e = hipLaunchCooperativeKernel((const void*)fused_all,
                                              dim3(GRID), dim3(256), args,
                                              0, stream);
    if (e != hipSuccess) {
        // Fallback: proven 3-kernel pipeline (identical outputs).
        proj_norm_all<<<(NROWS_HIS + NROWS_CDD) / 8, 256, 0, stream>>>(
            his_repr, cdd_repr, W_sel, b_sel, Yall);
        attn_topk_kernel<<<NB, 512, 0, stream>>>(cdd_p, his_p,
                                                 out_idx_f, idx_i, w_w);
        gather_kernel<<<NB * NCDD * NK, 256, 0, stream>>>(his_emb, idx_i, w_w, out);
    }
}

// Round 13
// 167.348 us; speedup vs baseline: 4.2403x; 4.2403x over previous
//
#include <hip/hip_runtime.h>
#include <hip/hip_bf16.h>

// Problem constants
#define NB   64
#define NCDD 5
#define NHIS 100
#define ND   256
#define NK   10
#define TLD  23040          // T*L*D = 30*3*256
#define NSLOT4 (3200 * 5760)  // total f32x4 slots in his_activated
#define THRESH 0.1f
#define NEG_INF (-3.402823466e38f)
#define NROWS_HIS 6400      // 64*100
#define NROWS_CDD 320       // 64*5
#define GBLOCKS 2048        // fill-kernel geometry: 2048 x 256 grid-stride

typedef float f32x4 __attribute__((ext_vector_type(4)));

// ---------------------------------------------------------------------------
// Kernel 1: BYTE-IDENTICAL to R8/R9 (control).
// ---------------------------------------------------------------------------
__global__ __launch_bounds__(256) void proj_norm_all(
    const float* __restrict__ his_repr,
    const float* __restrict__ cdd_repr,
    const float* __restrict__ W,
    const float* __restrict__ bvec,
    float* __restrict__ Yall)
{
    __shared__ float red[4][8];
    const int r0  = blockIdx.x * 8;
    const int tid = threadIdx.x;
    const int sub = tid & 3;
    const int grp = tid >> 2;
    const int wave = tid >> 6, lane = tid & 63;

    const float* __restrict__ X = (r0 < NROWS_HIS)
        ? (his_repr + (size_t)r0 * ND)
        : (cdd_repr + (size_t)(r0 - NROWS_HIS) * ND);

    float acc[4][8];
#pragma unroll
    for (int p = 0; p < 4; ++p)
#pragma unroll
        for (int r = 0; r < 8; ++r) acc[p][r] = 0.f;

#pragma unroll 4
    for (int i = 0; i < 16; ++i) {
        const int kb = sub * 4 + 16 * i;
        float4 x4[8];
#pragma unroll
        for (int r = 0; r < 8; ++r)
            x4[r] = *(const float4*)(X + (size_t)r * ND + kb);
#pragma unroll
        for (int p = 0; p < 4; ++p) {
            const int d = p * 64 + grp;
            const float4 w4 = *(const float4*)(W + (size_t)d * ND + kb);
#pragma unroll
            for (int r = 0; r < 8; ++r)
                acc[p][r] += w4.x * x4[r].x + w4.y * x4[r].y
                           + w4.z * x4[r].z + w4.w * x4[r].w;
        }
    }

#pragma unroll
    for (int p = 0; p < 4; ++p)
#pragma unroll
        for (int r = 0; r < 8; ++r) {
            float v = acc[p][r];
            v += __shfl_xor(v, 1);
            v += __shfl_xor(v, 2);
            acc[p][r] = v;
        }

    float bias[4];
#pragma unroll
    for (int p = 0; p < 4; ++p) bias[p] = bvec[p * 64 + grp];

    float ss[8];
#pragma unroll
    for (int r = 0; r < 8; ++r) {
        float t = 0.f;
#pragma unroll
        for (int p = 0; p < 4; ++p) {
            const float y = acc[p][r] + bias[p];
            acc[p][r] = y;
            t += y * y;
        }
        for (int off = 32; off; off >>= 1) t += __shfl_xor(t, off);
        ss[r] = t;
    }
    if (lane == 0) {
#pragma unroll
        for (int r = 0; r < 8; ++r) red[wave][r] = ss[r];
    }
    __syncthreads();

#pragma unroll
    for (int r = 0; r < 8; ++r) {
        const float s = 0.25f * (red[0][r] + red[1][r] + red[2][r] + red[3][r]);
        const float scale = 1.0f / fmaxf(sqrtf(s), 1e-12f);
        if (sub == 0) {
#pragma unroll
            for (int p = 0; p < 4; ++p)
                Yall[(size_t)(r0 + r) * ND + p * 64 + grp] = acc[p][r] * scale;
        }
    }
}

// ---------------------------------------------------------------------------
// Kernel 2: BYTE-IDENTICAL to R8/R9 (control).
// ---------------------------------------------------------------------------
__global__ __launch_bounds__(512) void attn_topk_kernel(
    const float* __restrict__ cdd_p,
    const float* __restrict__ his_p,
    float* __restrict__ out_idx_f,
    int* __restrict__ ws_idx,
    float* __restrict__ ws_w)
{
    __shared__ float attn_s[NCDD][128];
    const int b   = blockIdx.x;
    const int tid = threadIdx.x;
    const int sub = tid & 3, grp = tid >> 2;
    const int wave = tid >> 6, lane = tid & 63;

    const float* __restrict__ cbase = cdd_p + (size_t)b * NCDD * ND;
    const float* __restrict__ hbase = his_p + (size_t)b * NHIS * ND;

#pragma unroll
    for (int it = 0; it < 4; ++it) {
        const int task = it * 128 + grp;
        if (task < NCDD * NHIS) {
            const int c = task / NHIS, h = task - c * NHIS;
            const float* __restrict__ crow = cbase + (size_t)c * ND;
            const float* __restrict__ hrow = hbase + (size_t)h * ND;
            float a = 0.f;
#pragma unroll
            for (int i = 0; i < 16; ++i) {
                const int kb = sub * 4 + 16 * i;
                const float4 cv = *(const float4*)(crow + kb);
                const float4 hv = *(const float4*)(hrow + kb);
                a += cv.x * hv.x + cv.y * hv.y + cv.z * hv.z + cv.w * hv.w;
            }
            a += __shfl_xor(a, 1);
            a += __shfl_xor(a, 2);
            if (sub == 0) attn_s[c][h] = a;
        }
    }
    __syncthreads();

    if (wave < NCDD) {
        const int c = wave;
        float v0 = attn_s[c][lane];
        float v1 = (lane + 64 < NHIS) ? attn_s[c][lane + 64] : NEG_INF;
#pragma unroll
        for (int k = 0; k < NK; ++k) {
            float lv; int li;
            if (v1 > v0) { lv = v1; li = lane + 64; }
            else         { lv = v0; li = lane; }            // tie -> lower idx
            for (int off = 1; off < 64; off <<= 1) {
                const float ov = __shfl_xor(lv, off);
                const int   oi = __shfl_xor(li, off);
                if (ov > lv || (ov == lv && oi < li)) { lv = ov; li = oi; }
            }
            if (lane == 0) {
                const float w = (lv < THRESH) ? 0.0f : lv;
                const int g = (b * NCDD + c) * NK + k;
                ws_idx[g] = li;
                ws_w[g]   = w;
                out_idx_f[g] = (float)li;
            }
            if (li == lane)            v0 = NEG_INF;
            else if (li == lane + 64)  v1 = NEG_INF;
        }
    }
}

// ---------------------------------------------------------------------------
// Kernel 3: FLAT-STREAM gather. Treat his_activated as 18.43M f32x4 slots;
// grid-stride with the fill kernel's own geometry (2048x256, which the
// harness fill drives at 6.6 TB/s). slot -> (row g, offset r) via const
// division; w/idx are wave-uniform (256 consecutive slots per wave vs 5760
// slots per row) -> single broadcast L2 fetch. Dst is globally sequential;
// w==0 lanes skip the source read. No per-row blocks, no imbalance, no
// per-block ramp/drain.
// ---------------------------------------------------------------------------
__global__ __launch_bounds__(256) void gather_flat(
    const float* __restrict__ his_emb,
    const int* __restrict__ ws_idx,
    const float* __restrict__ ws_w,
    float* __restrict__ out)
{
    const int S = GBLOCKS * 256;
    const f32x4* __restrict__ src4 = (const f32x4*)his_emb;
    f32x4* __restrict__ dst4 = (f32x4*)out;

#pragma unroll 4
    for (int i = blockIdx.x * 256 + threadIdx.x; i < NSLOT4; i += S) {
        const int g = i / 5760;            // output row (b*50 + c*10 + k)
        const int r = i - g * 5760;        // f32x4 offset within row
        const float w = ws_w[g];
        f32x4 v = {0.f, 0.f, 0.f, 0.f};
        if (w != 0.0f) {
            const int b = g / (NCDD * NK);
            const int idx = ws_idx[g];
            v = src4[(size_t)(b * NHIS + idx) * 5760 + r] * w;
        }
        dst4[i] = v;
    }
}

// ---------------------------------------------------------------------------
extern "C" void kernel_launch(void* const* d_in, const int* in_sizes, int n_in,
                              void* d_out, int out_size, void* d_ws, size_t ws_size,
                              hipStream_t stream)
{
    const float* cdd_repr = (const float*)d_in[0];   // (64,5,256)
    const float* his_repr = (const float*)d_in[1];   // (64,100,256)
    const float* his_emb  = (const float*)d_in[2];   // (64,100,30,3,256)
    const float* W_sel    = (const float*)d_in[3];   // (256,256)
    const float* b_sel    = (const float*)d_in[4];   // (256,)
    float* out = (float*)d_out;

    // Workspace layout
    char* ws = (char*)d_ws;
    float* Yall  = (float*)ws;                       // 6720 rows * 256 * 4
    float* his_p = Yall;                             // rows [0, 6400)
    float* cdd_p = Yall + (size_t)NROWS_HIS * ND;    // rows [6400, 6720)
    int*   idx_i = (int*)  (ws + 6881280);           // 3200*4
    float* w_w   = (float*)(ws + 6894080);           // 3200*4

    // Output: his_activated [73,728,000] then idx [3200] (as float values)
    float* out_idx_f = out + (size_t)NB * NCDD * NK * TLD;

    proj_norm_all<<<(NROWS_HIS + NROWS_CDD) / 8, 256, 0, stream>>>(
        his_repr, cdd_repr, W_sel, b_sel, Yall);
    attn_topk_kernel<<<NB, 512, 0, stream>>>(cdd_p, his_p,
                                             out_idx_f, idx_i, w_w);
    gather_flat<<<GBLOCKS, 256, 0, stream>>>(his_emb, idx_i, w_w, out);
}